// Round 6
// baseline (145.732 us; speedup 1.0000x reference)
//
#include <hip/hip_runtime.h>
#include <hip/hip_bf16.h>
#include <hip/hip_fp16.h>
#include <stdint.h>

#define K_DIM 4096
#define N_DIM 11008
#define M_DIM 512
#define PK_ROW 5504          // int32 code-words per k-row (one per n-pair)
#define SC_ROW 172           // scale blocks per k-row

typedef __attribute__((ext_vector_type(4))) float f32x4;
typedef __attribute__((ext_vector_type(4))) int i32x4;
typedef __attribute__((ext_vector_type(4))) unsigned int u32x4;
typedef __attribute__((ext_vector_type(8))) _Float16 half8;
typedef __attribute__((ext_vector_type(8))) short bf16x8;

__constant__ float NF4[16] = {
    -1.0f, -0.6961928009986877f, -0.5250730514526367f, -0.39491748809814453f,
    -0.28444138169288635f, -0.18477343022823334f, -0.09105003625154495f, 0.0f,
    0.07958029955625534f, 0.16093020141124725f, 0.24611230194568634f,
    0.33791524171829224f, 0.44070982933044434f, 0.5626170039176941f,
    0.7229568362236023f, 1.0f};

union H8 { u32x4 v; half8 h; };

__device__ __forceinline__ unsigned h2mul(unsigned a, unsigned b) {
  union { __half2 h; unsigned u; } x, y, r;
  x.u = a; y.u = b;
  r.h = x.h * y.h;           // v_pk_mul_f16
  return r.u;
}
__device__ __forceinline__ unsigned hpack(float a, float b) {
  union { __half2 h; unsigned u; } c;
  c.h = __floats2half2_rn(a, b);
  return c.u;
}
__device__ __forceinline__ unsigned f2bf(float v) {  // for fallback kernel
  union { __hip_bfloat16 h; unsigned short u; } cv;
  cv.h = __float2bfloat16(v);
  return (unsigned)cv.u;
}

// ---- pre-pass 1: x fp32 -> f16, MFMA-fragment-block layout ----
// block (m16,k32) = 1KB; u32 idx = (m16*128+k32)*256 + lane*4
// lane l: A[m16*16+(l&15)][k32*32+(l>>4)*8 .. +8)
__global__ __launch_bounds__(256) void conv_a16(const float* __restrict__ x,
                                                unsigned* __restrict__ wsa) {
  const int wid = blockIdx.x * 4 + (threadIdx.x >> 6);
  const int lane = threadIdx.x & 63;
  const int m16 = wid >> 7, k32 = wid & 127;
  const int m = m16 * 16 + (lane & 15);
  const int k = k32 * 32 + (lane >> 4) * 8;
  const float* src = x + (size_t)m * K_DIM + k;
  f32x4 v0 = *(const f32x4*)src;
  f32x4 v1 = *(const f32x4*)(src + 4);
  u32x4 d;
  d[0] = hpack(v0[0], v0[1]);
  d[1] = hpack(v0[2], v0[3]);
  d[2] = hpack(v1[0], v1[1]);
  d[3] = hpack(v1[2], v1[3]);
  *(u32x4*)(wsa + (size_t)wid * 256 + lane * 4) = d;
}

// ---- pre-pass 2: transpose-compact codes ----
// out: uint8 byte (n, kp) = code(2kp,n)<<4 | code(2kp+1,n), stored as dwords:
//      dword D = ((n>>4)*512 + (kp>>2))*16 + (n&15)
__global__ __launch_bounds__(256) void prep_codes(const int* __restrict__ packed,
                                                  unsigned* __restrict__ codes) {
  const int b = blockIdx.x;
  const int kt = b & 63;   // k-tile of 64
  const int nt = b >> 6;   // n-tile of 128 (0..85)
  __shared__ unsigned char Sb[128 * 36];  // [n_local][kp_local], pad 36
  const int t = threadIdx.x;
  const int npl = t & 63;
  const int kq = t >> 6;
  const int np = nt * 64 + npl;
#pragma unroll
  for (int i = 0; i < 8; ++i) {
    const int kpl = kq + i * 4;               // 0..31
    const int k = kt * 64 + kpl * 2;
    const int w0 = packed[(size_t)k * PK_ROW + np];
    const int w1 = packed[(size_t)(k + 1) * PK_ROW + np];
    Sb[(npl * 2) * 36 + kpl] =
        (unsigned char)((((w0 >> 4) & 15) << 4) | ((w1 >> 4) & 15));  // even n
    Sb[(npl * 2 + 1) * 36 + kpl] =
        (unsigned char)(((w0 & 15) << 4) | (w1 & 15));                // odd n
  }
  __syncthreads();
#pragma unroll
  for (int i = 0; i < 4; ++i) {
    const int lin = t + 256 * i;              // 0..1023
    const int n16 = lin & 15;
    const int kp4l = (lin >> 4) & 7;
    const int nb16l = lin >> 7;               // 0..7
    const unsigned v = *(const unsigned*)(Sb + (nb16l * 16 + n16) * 36 + kp4l * 4);
    const size_t D = ((size_t)(nt * 8 + nb16l) * 512 + kt * 8 + kp4l) * 16 + n16;
    codes[D] = v;
  }
}

// ---- pre-pass 3: scales fp32 [k][nb] -> f16x2 pairs [nb][kp] ----
__global__ __launch_bounds__(256) void prep_scales(const float* __restrict__ scales,
                                                   unsigned* __restrict__ scalesp) {
  const int g = blockIdx.x * 256 + threadIdx.x;
  if (g >= SC_ROW * 2048) return;
  const int kp = g / SC_ROW;
  const int nb = g - kp * SC_ROW;
  const float s0 = scales[(size_t)(2 * kp) * SC_ROW + nb];
  const float s1 = scales[(size_t)(2 * kp + 1) * SC_ROW + nb];
  scalesp[(size_t)nb * 2048 + kp] = hpack(s0, s1);
}

// ---- main: barrier-free fused NF4 GEMM, f16 MFMA ----
// block 128m x 64n, 4 waves, wave-tile 128m x 16n (R6: was 64x32 -> halves
// dequant work per MFMA). Bank-replicated LUT (32 copies, 32KB) kills the
// random-gather conflicts (R5: 1.2e7 conflict-cycles).
__global__ __launch_bounds__(256, 3) void nf4_gemm16(
    const unsigned* __restrict__ codes, const unsigned* __restrict__ scalesp,
    const unsigned* __restrict__ wsa, const float* __restrict__ bias,
    float* __restrict__ out) {
  const int bid = blockIdx.x;
  const int x = bid & 7;
  const int local = bid >> 3;          // 0..87
  const int m_idx = local & 3;
  const int nl = local >> 2;           // 0..21
  const int S = (x < 4) ? x * 22 : 88 + (x - 4) * 21;
  const int cnt = (x < 4) ? 22 : 21;
  if (nl >= cnt) return;               // block-uniform
  const int n_tile = (S + nl) * 64;
  const int m_tile = m_idx * 128;

  // replicated LUT: dword index = byte*32 + bank; lane uses bank = lane&31
  __shared__ unsigned LutR[256 * 32];
  const int t = threadIdx.x;
  {
    const int c = t & 31;              // bank copy
    const int b0 = t >> 5;             // 0..7
#pragma unroll
    for (int i = 0; i < 32; ++i) {
      const int b = b0 + 8 * i;        // byte value
      LutR[b * 32 + c] = hpack(NF4[(b >> 4) & 15], NF4[b & 15]);
    }
  }
  __syncthreads();

  const int lane = t & 63;
  const int wid = t >> 6;
  const int wn = wid * 16;             // wave's n-slice within block
  const int l15 = lane & 15;
  const int kslice = lane >> 4;        // 0..3
  const int lb = lane & 31;            // private LUT bank
  const int m16w = m_tile >> 4;        // wave covers ALL 8 m16-blocks
  const int nf0 = (n_tile + wn) >> 4;
  const int nb64 = n_tile >> 6;

  // u32 base indices; per k-step s add: codes +64, scales +16, A +256
  const unsigned cb = (unsigned)nf0 * 8192 + lane;
  const unsigned sb = (unsigned)nb64 * 2048 + kslice * 4;
  unsigned ab[8];
#pragma unroll
  for (int fm = 0; fm < 8; ++fm)
    ab[fm] = (unsigned)(m16w + fm) * 32768 + lane * 4;

  f32x4 acc[8];
#pragma unroll
  for (int i = 0; i < 8; ++i) acc[i] = (f32x4){0.f, 0.f, 0.f, 0.f};

  auto LOAD = [&](int s, unsigned& c0, u32x4& sv, u32x4* A) {
    c0 = codes[cb + 64u * s];
    sv = *(const u32x4*)(scalesp + sb + 16u * s);
#pragma unroll
    for (int fm = 0; fm < 8; ++fm)
      A[fm] = *(const u32x4*)(wsa + ab[fm] + 256u * s);
  };
  auto STEP = [&](unsigned c0, const u32x4& sv, const u32x4* A) {
    H8 B;
    {
      const unsigned b0 = (c0 & 255u);
      const unsigned b1 = (c0 >> 8) & 255u;
      const unsigned b2 = (c0 >> 16) & 255u;
      const unsigned b3 = (c0 >> 24);
      B.v[0] = h2mul(LutR[(b0 << 5) | lb], sv[0]);
      B.v[1] = h2mul(LutR[(b1 << 5) | lb], sv[1]);
      B.v[2] = h2mul(LutR[(b2 << 5) | lb], sv[2]);
      B.v[3] = h2mul(LutR[(b3 << 5) | lb], sv[3]);
    }
#pragma unroll
    for (int fm = 0; fm < 8; ++fm) {
      H8 a; a.v = A[fm];
      acc[fm] = __builtin_amdgcn_mfma_f32_16x16x32_f16(a.h, B.h, acc[fm], 0, 0, 0);
    }
  };

  unsigned Xc, Yc;
  u32x4 Xs, Ys;
  u32x4 XA[8], YA[8];
  LOAD(0, Xc, Xs, XA);
#pragma unroll 1
  for (int s = 0; s < 128; s += 2) {
    const int s1 = (s + 1 < 128) ? s + 1 : 127;
    const int s2 = (s + 2 < 128) ? s + 2 : 127;
    LOAD(s1, Yc, Ys, YA);
    STEP(Xc, Xs, XA);
    LOAD(s2, Xc, Xs, XA);
    STEP(Yc, Ys, YA);
  }

  // epilogue: C layout col=l15, row=kslice*4+r
#pragma unroll
  for (int fm = 0; fm < 8; ++fm) {
    const int gc = n_tile + wn + l15;
    const float bi = bias[gc];
#pragma unroll
    for (int r = 0; r < 4; ++r) {
      const int gr = m_tile + fm * 16 + kslice * 4 + r;
      out[(size_t)gr * N_DIM + gc] = acc[fm][r] + bi;
    }
  }
}

// ---- fallback (round-1 kernel, proven 155us): used only if ws too small ----
#define FLDS 72
__global__ __launch_bounds__(256) void nf4_gemm_fused(
    const float* __restrict__ x, const int* __restrict__ packed,
    const float* __restrict__ scales, const float* __restrict__ bias,
    float* __restrict__ out) {
  __shared__ unsigned short Alds[128 * FLDS];
  __shared__ unsigned short Blds[128 * FLDS];
  __shared__ float2 Lut[256];
  const int t = threadIdx.x;
  const int bid = blockIdx.x;
  const int swz = (bid & 7) * 43 + (bid >> 3);
  const int m_tile = (swz / 86) * 128;
  const int n_tile = (swz % 86) * 128;
  Lut[t] = make_float2(NF4[(t >> 4) & 15], NF4[t & 15]);
  const int lane = t & 63;
  const int wid = t >> 6;
  const int wm = (wid >> 1) * 64;
  const int wn = (wid & 1) * 64;
  const int l15 = lane & 15;
  const int l4 = lane >> 4;
  f32x4 acc[4][4];
#pragma unroll
  for (int i = 0; i < 4; ++i)
#pragma unroll
    for (int j = 0; j < 4; ++j) acc[i][j] = (f32x4){0.f, 0.f, 0.f, 0.f};
  const int mlane = t & 15;
  const int n_sub = mlane * 8;
  const int k_sub = 4 * (((t >> 4) + mlane) & 15);
  const int c4 = t & 15;
  const int r0 = t >> 4;
  for (int k0 = 0; k0 < K_DIM; k0 += 64) {
    __syncthreads();
#pragma unroll
    for (int i = 0; i < 8; ++i) {
      const int row = r0 + 16 * i;
      f32x4 xv = *(const f32x4*)(x + (size_t)(m_tile + row) * K_DIM + k0 + c4 * 4);
      uint2 d;
      d.x = f2bf(xv[0]) | (f2bf(xv[1]) << 16);
      d.y = f2bf(xv[2]) | (f2bf(xv[3]) << 16);
      *(uint2*)(&Alds[row * FLDS + c4 * 4]) = d;
    }
    {
      const int* pk = packed + (size_t)(k0 + k_sub) * PK_ROW + ((n_tile + n_sub) >> 1);
      i32x4 w[4];
      float s[4];
#pragma unroll
      for (int kk = 0; kk < 4; ++kk) {
        w[kk] = *(const i32x4*)(pk + (size_t)kk * PK_ROW);
        s[kk] = scales[(size_t)(k0 + k_sub + kk) * SC_ROW + ((n_tile + n_sub) >> 6)];
      }
      float v[4][8];
#pragma unroll
      for (int kk = 0; kk < 4; ++kk)
#pragma unroll
        for (int e = 0; e < 4; ++e) {
          const int b = w[kk][e] & 0xFF;
          const float2 p = Lut[b];
          v[kk][2 * e] = p.x * s[kk];
          v[kk][2 * e + 1] = p.y * s[kk];
        }
#pragma unroll
      for (int j = 0; j < 8; ++j) {
        uint2 d;
        d.x = f2bf(v[0][j]) | (f2bf(v[1][j]) << 16);
        d.y = f2bf(v[2][j]) | (f2bf(v[3][j]) << 16);
        *(uint2*)(&Blds[(n_sub + j) * FLDS + k_sub]) = d;
      }
    }
    __syncthreads();
#pragma unroll
    for (int ks = 0; ks < 2; ++ks) {
      bf16x8 af[4], bfv[4];
#pragma unroll
      for (int fm = 0; fm < 4; ++fm)
        af[fm] = *(const bf16x8*)(&Alds[(wm + fm * 16 + l15) * FLDS + ks * 32 + l4 * 8]);
#pragma unroll
      for (int fn = 0; fn < 4; ++fn)
        bfv[fn] = *(const bf16x8*)(&Blds[(wn + fn * 16 + l15) * FLDS + ks * 32 + l4 * 8]);
#pragma unroll
      for (int fm = 0; fm < 4; ++fm)
#pragma unroll
        for (int fn = 0; fn < 4; ++fn)
          acc[fm][fn] = __builtin_amdgcn_mfma_f32_16x16x32_bf16(af[fm], bfv[fn], acc[fm][fn], 0, 0, 0);
    }
  }
#pragma unroll
  for (int fn = 0; fn < 4; ++fn) {
    const float bi = bias[n_tile + wn + fn * 16 + l15];
#pragma unroll
    for (int fm = 0; fm < 4; ++fm)
#pragma unroll
      for (int r = 0; r < 4; ++r) {
        const int gr = m_tile + wm + fm * 16 + l4 * 4 + r;
        out[(size_t)gr * N_DIM + n_tile + wn + fn * 16 + l15] = acc[fm][fn][r] + bi;
      }
  }
}

extern "C" void kernel_launch(void* const* d_in, const int* in_sizes, int n_in,
                              void* d_out, int out_size, void* d_ws, size_t ws_size,
                              hipStream_t stream) {
  const float* x = (const float*)d_in[0];
  const int* packed = (const int*)d_in[1];
  const float* scales = (const float*)d_in[2];
  const float* bias = (const float*)d_in[3];
  float* out = (float*)d_out;

  const size_t A_BYTES = (size_t)M_DIM * K_DIM * 2;            // 4,194,304
  const size_t C_BYTES = (size_t)688 * 512 * 16 * 4;           // 22,544,384
  const size_t S_BYTES = (size_t)SC_ROW * 2048 * 4;            // 1,409,024
  const size_t need = A_BYTES + C_BYTES + S_BYTES;

  if (ws_size >= need) {
    unsigned* wsa = (unsigned*)d_ws;
    unsigned* codes = (unsigned*)((char*)d_ws + A_BYTES);
    unsigned* scalesp = (unsigned*)((char*)d_ws + A_BYTES + C_BYTES);
    conv_a16<<<dim3(1024), dim3(256), 0, stream>>>(x, wsa);
    prep_codes<<<dim3(5504), dim3(256), 0, stream>>>(packed, codes);
    prep_scales<<<dim3(1376), dim3(256), 0, stream>>>(scales, scalesp);
    nf4_gemm16<<<dim3(704), dim3(256), 0, stream>>>(codes, scalesp, wsa, bias, out);
  } else {
    nf4_gemm_fused<<<dim3(344), dim3(256), 0, stream>>>(x, packed, scales, bias, out);
  }
}

// Round 7
// 115.146 us; speedup vs baseline: 1.2656x; 1.2656x over previous
//
#include <hip/hip_runtime.h>
#include <hip/hip_bf16.h>
#include <hip/hip_fp16.h>
#include <stdint.h>

#define K_DIM 4096
#define N_DIM 11008
#define M_DIM 512
#define PK_ROW 5504          // int32 code-words per k-row (one per n-pair)
#define SC_ROW 172           // scale blocks per k-row

typedef __attribute__((ext_vector_type(4))) float f32x4;
typedef __attribute__((ext_vector_type(4))) int i32x4;
typedef __attribute__((ext_vector_type(4))) unsigned int u32x4;
typedef __attribute__((ext_vector_type(8))) _Float16 half8;
typedef __attribute__((ext_vector_type(8))) short bf16x8;

__constant__ float NF4[16] = {
    -1.0f, -0.6961928009986877f, -0.5250730514526367f, -0.39491748809814453f,
    -0.28444138169288635f, -0.18477343022823334f, -0.09105003625154495f, 0.0f,
    0.07958029955625534f, 0.16093020141124725f, 0.24611230194568634f,
    0.33791524171829224f, 0.44070982933044434f, 0.5626170039176941f,
    0.7229568362236023f, 1.0f};

union H8 { u32x4 v; half8 h; };

__device__ __forceinline__ unsigned h2mul(unsigned a, unsigned b) {
  union { __half2 h; unsigned u; } x, y, r;
  x.u = a; y.u = b;
  r.h = x.h * y.h;           // v_pk_mul_f16
  return r.u;
}
__device__ __forceinline__ unsigned hpack(float a, float b) {
  union { __half2 h; unsigned u; } c;
  c.h = __floats2half2_rn(a, b);
  return c.u;
}
__device__ __forceinline__ unsigned f2bf(float v) {  // for fallback kernel
  union { __hip_bfloat16 h; unsigned short u; } cv;
  cv.h = __float2bfloat16(v);
  return (unsigned)cv.u;
}
// global -> LDS direct DMA, 16B/lane. LDS dest = uniform base + lane*16 (HW).
__device__ __forceinline__ void gld16(const unsigned* g, unsigned* l) {
  __builtin_amdgcn_global_load_lds(
      (const __attribute__((address_space(1))) unsigned*)(const void*)g,
      (__attribute__((address_space(3))) unsigned*)(void*)l, 16, 0, 0);
}

// ---- pre-pass 1: x fp32 -> f16, MFMA-fragment-block layout ----
// unit (m16,k32) = 1KB; u32 idx = (m16*128+k32)*256 + lane*4
// lane l: A[m16*16+(l&15)][k32*32+(l>>4)*8 .. +8)
__global__ __launch_bounds__(256) void conv_a16(const float* __restrict__ x,
                                                unsigned* __restrict__ wsa) {
  const int wid = blockIdx.x * 4 + (threadIdx.x >> 6);
  const int lane = threadIdx.x & 63;
  const int m16 = wid >> 7, k32 = wid & 127;
  const int m = m16 * 16 + (lane & 15);
  const int k = k32 * 32 + (lane >> 4) * 8;
  const float* src = x + (size_t)m * K_DIM + k;
  f32x4 v0 = *(const f32x4*)src;
  f32x4 v1 = *(const f32x4*)(src + 4);
  u32x4 d;
  d[0] = hpack(v0[0], v0[1]);
  d[1] = hpack(v0[2], v0[3]);
  d[2] = hpack(v1[0], v1[1]);
  d[3] = hpack(v1[2], v1[3]);
  *(u32x4*)(wsa + (size_t)wid * 256 + lane * 4) = d;
}

// ---- pre-pass 2: transpose-compact codes ----
// out: uint8 byte (n, kp) = code(2kp,n)<<4 | code(2kp+1,n), stored as dwords:
//      dword D = ((n>>4)*512 + (kp>>2))*16 + (n&15)
__global__ __launch_bounds__(256) void prep_codes(const int* __restrict__ packed,
                                                  unsigned* __restrict__ codes) {
  const int b = blockIdx.x;
  const int kt = b & 63;   // k-tile of 64
  const int nt = b >> 6;   // n-tile of 128 (0..85)
  __shared__ unsigned char Sb[128 * 36];  // [n_local][kp_local], pad 36
  const int t = threadIdx.x;
  const int npl = t & 63;
  const int kq = t >> 6;
  const int np = nt * 64 + npl;
#pragma unroll
  for (int i = 0; i < 8; ++i) {
    const int kpl = kq + i * 4;               // 0..31
    const int k = kt * 64 + kpl * 2;
    const int w0 = packed[(size_t)k * PK_ROW + np];
    const int w1 = packed[(size_t)(k + 1) * PK_ROW + np];
    Sb[(npl * 2) * 36 + kpl] =
        (unsigned char)((((w0 >> 4) & 15) << 4) | ((w1 >> 4) & 15));  // even n
    Sb[(npl * 2 + 1) * 36 + kpl] =
        (unsigned char)(((w0 & 15) << 4) | (w1 & 15));                // odd n
  }
  __syncthreads();
#pragma unroll
  for (int i = 0; i < 4; ++i) {
    const int lin = t + 256 * i;              // 0..1023
    const int n16 = lin & 15;
    const int kp4l = (lin >> 4) & 7;
    const int nb16l = lin >> 7;               // 0..7
    const unsigned v = *(const unsigned*)(Sb + (nb16l * 16 + n16) * 36 + kp4l * 4);
    const size_t D = ((size_t)(nt * 8 + nb16l) * 512 + kt * 8 + kp4l) * 16 + n16;
    codes[D] = v;
  }
}

// ---- pre-pass 3: scales fp32 [k][nb] -> f16x2 pairs [nb][kp] ----
__global__ __launch_bounds__(256) void prep_scales(const float* __restrict__ scales,
                                                   unsigned* __restrict__ scalesp) {
  const int g = blockIdx.x * 256 + threadIdx.x;
  if (g >= SC_ROW * 2048) return;
  const int kp = g / SC_ROW;
  const int nb = g - kp * SC_ROW;
  const float s0 = scales[(size_t)(2 * kp) * SC_ROW + nb];
  const float s1 = scales[(size_t)(2 * kp + 1) * SC_ROW + nb];
  scalesp[(size_t)nb * 2048 + kp] = hpack(s0, s1);
}

// ---- main: fused NF4 GEMM, f16 MFMA, LDS-staged A ----
// Block 64m x 128n, 4 waves 2x2, wave-tile 32m x 64n. Grid 688 (8x86, 90%
// balance). A staged per-block via global_load_lds into 2x8KB dbuf (R7: R5/R6
// were L1-bound on (N/wn)*4MB of redundant A VMEM reads; LDS staging cuts A
// traffic to (N/BN)*4MB = 344MB and moves reads to the LDS pipe).
__global__ __launch_bounds__(256, 3) void nf4_gemm16(
    const unsigned* __restrict__ codes, const unsigned* __restrict__ scalesp,
    const unsigned* __restrict__ wsa, const float* __restrict__ bias,
    float* __restrict__ out) {
  __shared__ unsigned LutR[256 * 32];        // replicated LUT, 32KB
  __shared__ __align__(16) unsigned Alds[2][2048];  // A dbuf 2x8KB

  const int bid = blockIdx.x;
  const int x = bid & 7;
  const int local = bid >> 3;          // 0..87
  const int m_idx = local & 7;         // 8 m-tiles of 64
  const int nl = local >> 3;           // 0..10
  const int S = (x < 6) ? x * 11 : 66 + (x - 6) * 10;  // XCD n-partition
  const int cnt = (x < 6) ? 11 : 10;   // 86 = 6*11 + 2*10
  if (nl >= cnt) return;               // 16 idle blocks of 704... grid is 704
  const int n_tile = (S + nl) * 128;
  const int m_tile = m_idx * 64;

  const int t = threadIdx.x;
  {  // replicated LUT: dword idx = byte*32 + copy; lane uses copy=lane&31
    const int c = t & 31;
    const int b0 = t >> 5;
#pragma unroll
    for (int i = 0; i < 32; ++i) {
      const int b = b0 + 8 * i;
      LutR[b * 32 + c] = hpack(NF4[(b >> 4) & 15], NF4[b & 15]);
    }
  }

  const int lane = t & 63;
  const int wid = t >> 6;
  const int wm2 = wid >> 1;            // m-half (32 rows)
  const int wnh = wid & 1;             // n-half (64 cols)
  const int l15 = lane & 15;
  const int kslice = lane >> 4;
  const int lb = lane & 31;
  const int nf0 = (n_tile >> 4) + wnh * 4;   // first n16 block (4 per wave)
  const int nb64 = (n_tile >> 6) + wnh;

  unsigned cb[4];
#pragma unroll
  for (int j = 0; j < 4; ++j) cb[j] = (unsigned)(nf0 + j) * 8192 + lane;
  const unsigned sb = (unsigned)nb64 * 2048 + kslice * 4;

  f32x4 acc[2][4];
#pragma unroll
  for (int i = 0; i < 2; ++i)
#pragma unroll
    for (int j = 0; j < 4; ++j) acc[i][j] = (f32x4){0.f, 0.f, 0.f, 0.f};

  // stage chunk ch (64 k) into buf: 8 units of 1KB; wave wid does units
  // (wid*2, wid*2+1) = m16_local wid, k32_local {0,1}
  auto stageA = [&](int ch, int bufi) {
    const unsigned u0 = (unsigned)(m_idx * 4 + wid) * 128 + ch * 2;
    const unsigned* g = wsa + (size_t)u0 * 256 + lane * 4;
    unsigned* l = &Alds[bufi][wid * 512];
    gld16(g, l);
    gld16(g + 256, l + 256);
  };
  // codes+scales for chunk ch -> regs (8 dwords + 2 x4)
  auto loadB = [&](int ch, unsigned* c, u32x4* sv) {
#pragma unroll
    for (int ks = 0; ks < 2; ++ks) {
      const unsigned so = 64u * (unsigned)(2 * ch + ks);
#pragma unroll
      for (int j = 0; j < 4; ++j) c[ks * 4 + j] = codes[cb[j] + so];
      sv[ks] = *(const u32x4*)(scalesp + sb + 16u * (unsigned)(2 * ch + ks));
    }
  };
  auto compute = [&](int cur, const unsigned* c, const u32x4* sv) {
#pragma unroll
    for (int ks = 0; ks < 2; ++ks) {
      H8 a0, a1;
      a0.v = *(const u32x4*)(&Alds[cur][((wm2 * 2 + 0) * 2 + ks) * 256 + lane * 4]);
      a1.v = *(const u32x4*)(&Alds[cur][((wm2 * 2 + 1) * 2 + ks) * 256 + lane * 4]);
      const u32x4 s4 = sv[ks];
#pragma unroll
      for (int j = 0; j < 4; ++j) {
        const unsigned cw = c[ks * 4 + j];
        H8 B;
        B.v[0] = h2mul(LutR[((cw & 255u) << 5) | lb], s4[0]);
        B.v[1] = h2mul(LutR[(((cw >> 8) & 255u) << 5) | lb], s4[1]);
        B.v[2] = h2mul(LutR[(((cw >> 16) & 255u) << 5) | lb], s4[2]);
        B.v[3] = h2mul(LutR[((cw >> 24) << 5) | lb], s4[3]);
        acc[0][j] = __builtin_amdgcn_mfma_f32_16x16x32_f16(a0.h, B.h, acc[0][j], 0, 0, 0);
        acc[1][j] = __builtin_amdgcn_mfma_f32_16x16x32_f16(a1.h, B.h, acc[1][j], 0, 0, 0);
      }
    }
  };

  unsigned Xc[8], Yc[8];
  u32x4 Xs[2], Ys[2];

  stageA(0, 0);
  loadB(0, Xc, Xs);
  __syncthreads();  // LUT visible + chunk0 staged (compiler drains vmcnt)

#pragma unroll 1
  for (int cc = 0; cc < 32; ++cc) {
    const int c0 = 2 * cc;
    stageA(c0 + 1, 1);                  // c0+1 <= 63 always
    loadB(c0 + 1, Yc, Ys);
    compute(0, Xc, Xs);
    __syncthreads();
    if (cc < 31) {                      // chunk c0+2 exists only if cc<31
      stageA(c0 + 2, 0);
      loadB(c0 + 2, Xc, Xs);
    }
    compute(1, Yc, Ys);
    __syncthreads();
  }

  // epilogue: C layout col=l15, row=kslice*4+r
#pragma unroll
  for (int j = 0; j < 4; ++j) {
    const int gc = n_tile + wnh * 64 + j * 16 + l15;
    const float bi = bias[gc];
#pragma unroll
    for (int mf = 0; mf < 2; ++mf) {
#pragma unroll
      for (int r = 0; r < 4; ++r) {
        const int gr = m_tile + wm2 * 32 + mf * 16 + kslice * 4 + r;
        out[(size_t)gr * N_DIM + gc] = acc[mf][j][r] + bi;
      }
    }
  }
}

// ---- fallback (round-1 kernel, proven 155us): used only if ws too small ----
#define FLDS 72
__global__ __launch_bounds__(256) void nf4_gemm_fused(
    const float* __restrict__ x, const int* __restrict__ packed,
    const float* __restrict__ scales, const float* __restrict__ bias,
    float* __restrict__ out) {
  __shared__ unsigned short AldsF[128 * FLDS];
  __shared__ unsigned short BldsF[128 * FLDS];
  __shared__ float2 Lut[256];
  const int t = threadIdx.x;
  const int bid = blockIdx.x;
  const int swz = (bid & 7) * 43 + (bid >> 3);
  const int m_tile = (swz / 86) * 128;
  const int n_tile = (swz % 86) * 128;
  Lut[t] = make_float2(NF4[(t >> 4) & 15], NF4[t & 15]);
  const int lane = t & 63;
  const int wid = t >> 6;
  const int wm = (wid >> 1) * 64;
  const int wn = (wid & 1) * 64;
  const int l15 = lane & 15;
  const int l4 = lane >> 4;
  f32x4 acc[4][4];
#pragma unroll
  for (int i = 0; i < 4; ++i)
#pragma unroll
    for (int j = 0; j < 4; ++j) acc[i][j] = (f32x4){0.f, 0.f, 0.f, 0.f};
  const int mlane = t & 15;
  const int n_sub = mlane * 8;
  const int k_sub = 4 * (((t >> 4) + mlane) & 15);
  const int c4 = t & 15;
  const int r0 = t >> 4;
  for (int k0 = 0; k0 < K_DIM; k0 += 64) {
    __syncthreads();
#pragma unroll
    for (int i = 0; i < 8; ++i) {
      const int row = r0 + 16 * i;
      f32x4 xv = *(const f32x4*)(x + (size_t)(m_tile + row) * K_DIM + k0 + c4 * 4);
      uint2 d;
      d.x = f2bf(xv[0]) | (f2bf(xv[1]) << 16);
      d.y = f2bf(xv[2]) | (f2bf(xv[3]) << 16);
      *(uint2*)(&AldsF[row * FLDS + c4 * 4]) = d;
    }
    {
      const int* pk = packed + (size_t)(k0 + k_sub) * PK_ROW + ((n_tile + n_sub) >> 1);
      i32x4 w[4];
      float s[4];
#pragma unroll
      for (int kk = 0; kk < 4; ++kk) {
        w[kk] = *(const i32x4*)(pk + (size_t)kk * PK_ROW);
        s[kk] = scales[(size_t)(k0 + k_sub + kk) * SC_ROW + ((n_tile + n_sub) >> 6)];
      }
      float v[4][8];
#pragma unroll
      for (int kk = 0; kk < 4; ++kk)
#pragma unroll
        for (int e = 0; e < 4; ++e) {
          const int b = w[kk][e] & 0xFF;
          const float2 p = Lut[b];
          v[kk][2 * e] = p.x * s[kk];
          v[kk][2 * e + 1] = p.y * s[kk];
        }
#pragma unroll
      for (int j = 0; j < 8; ++j) {
        uint2 d;
        d.x = f2bf(v[0][j]) | (f2bf(v[1][j]) << 16);
        d.y = f2bf(v[2][j]) | (f2bf(v[3][j]) << 16);
        *(uint2*)(&BldsF[(n_sub + j) * FLDS + k_sub]) = d;
      }
    }
    __syncthreads();
#pragma unroll
    for (int ks = 0; ks < 2; ++ks) {
      bf16x8 af[4], bfv[4];
#pragma unroll
      for (int fm = 0; fm < 4; ++fm)
        af[fm] = *(const bf16x8*)(&AldsF[(wm + fm * 16 + l15) * FLDS + ks * 32 + l4 * 8]);
#pragma unroll
      for (int fn = 0; fn < 4; ++fn)
        bfv[fn] = *(const bf16x8*)(&BldsF[(wn + fn * 16 + l15) * FLDS + ks * 32 + l4 * 8]);
#pragma unroll
      for (int fm = 0; fm < 4; ++fm)
#pragma unroll
        for (int fn = 0; fn < 4; ++fn)
          acc[fm][fn] = __builtin_amdgcn_mfma_f32_16x16x32_bf16(af[fm], bfv[fn], acc[fm][fn], 0, 0, 0);
    }
  }
#pragma unroll
  for (int fn = 0; fn < 4; ++fn) {
    const float bi = bias[n_tile + wn + fn * 16 + l15];
#pragma unroll
    for (int fm = 0; fm < 4; ++fm)
#pragma unroll
      for (int r = 0; r < 4; ++r) {
        const int gr = m_tile + wm + fm * 16 + l4 * 4 + r;
        out[(size_t)gr * N_DIM + n_tile + wn + fn * 16 + l15] = acc[fm][fn][r] + bi;
      }
  }
}

extern "C" void kernel_launch(void* const* d_in, const int* in_sizes, int n_in,
                              void* d_out, int out_size, void* d_ws, size_t ws_size,
                              hipStream_t stream) {
  const float* x = (const float*)d_in[0];
  const int* packed = (const int*)d_in[1];
  const float* scales = (const float*)d_in[2];
  const float* bias = (const float*)d_in[3];
  float* out = (float*)d_out;

  const size_t A_BYTES = (size_t)M_DIM * K_DIM * 2;            // 4,194,304
  const size_t C_BYTES = (size_t)688 * 512 * 16 * 4;           // 22,544,384
  const size_t S_BYTES = (size_t)SC_ROW * 2048 * 4;            // 1,409,024
  const size_t need = A_BYTES + C_BYTES + S_BYTES;

  if (ws_size >= need) {
    unsigned* wsa = (unsigned*)d_ws;
    unsigned* codes = (unsigned*)((char*)d_ws + A_BYTES);
    unsigned* scalesp = (unsigned*)((char*)d_ws + A_BYTES + C_BYTES);
    conv_a16<<<dim3(1024), dim3(256), 0, stream>>>(x, wsa);
    prep_codes<<<dim3(5504), dim3(256), 0, stream>>>(packed, codes);
    prep_scales<<<dim3(1376), dim3(256), 0, stream>>>(scales, scalesp);
    nf4_gemm16<<<dim3(704), dim3(256), 0, stream>>>(codes, scalesp, wsa, bias, out);
  } else {
    nf4_gemm_fused<<<dim3(344), dim3(256), 0, stream>>>(x, packed, scales, bias, out);
  }
}